// Round 8
// baseline (146.768 us; speedup 1.0000x reference)
//
#include <hip/hip_runtime.h>
#include <stdint.h>

#define BATCH 8
#define HIN   28
#define CH    32
#define HO    14
#define NIN   784   // 28*28
#define NOUT  196   // 14*14

#define NPOS   (4 * NIN)          // 3136 128B-positions per block
#define WPI    224                // positions per block-iteration (28KB)
#define UNROLL 7
#define OUTER  (NPOS / WPI)       // 14
#define TILE_W (NOUT * CH)        // 6272 words

typedef float f32x4 __attribute__((ext_vector_type(4)));

// One workgroup per (b, p) with bijective per-image XCD chunking (consecutive
// windows -> same XCD -> per-L2 streams are long and sequential).
// Phase 0: per-window argmax codes for all windows of image b (L2-hot mu);
//          cmq[j][half] = (q*CH)<<16 | mask16 of channels selecting input
//          position j. Own-p threads write mu_out.
// Phase 1: FULLY DENSE read of the block's two contiguous 200KB Sigma slabs.
//          Wave-burst ordering: each wave's 7 in-flight loads cover one
//          contiguous 7KB span (page-local); block walks 28KB/iteration
//          sequentially. Plain (cached) loads — NT only on stores.
//          Branchless LDS scatter with q-rotated banks (kills the 8-way
//          conflict: bank was offset%32, q-independent across octets).
// Phase 2: 25KB tile -> global, un-rotated, fully coalesced, nontemporal.
// Each output word written exactly once (unique (r,dj) per channel):
// no init, no atomics, deterministic.
__global__ __launch_bounds__(256, 4) void vdp_pool_fused_kernel(
        const float* __restrict__ mu_in,
        const float* __restrict__ sigma_in,
        float* __restrict__ mu_out,
        float* __restrict__ sigma_out)
{
    __shared__ __align__(16) float out_tile[TILE_W + 64];  // +64 trash words
    __shared__ uint32_t cmq[NIN * 2];                      // [j][half]

    const int blk = blockIdx.x;                // b*NOUT + chunk-swizzled p
    const int b   = blk / NOUT;
    const int o2  = blk - b * NOUT;
    // bijective XCD chunking: nwg=196, q=24, r=4
    const int xcd = o2 & 7;
    const int m   = o2 >> 3;
    const int p   = (xcd < 4) ? xcd * 25 + m : 100 + (xcd - 4) * 24 + m;
    const int tid = threadIdx.x;

    // ---------------- Phase 0: window codes -> cmq (+ mu_out for own p) ----
    for (int w = tid; w < NOUT * 2; w += 256) {
        const int q2   = w >> 1;
        const int hf   = w & 1;
        const int qy = q2 / HO, qx = q2 - qy * HO;
        const float* base =
            mu_in + (((size_t)b * HIN + 2 * qy) * HIN + 2 * qx) * CH + hf * 16;

        uint32_t kqh = 0;
        #pragma unroll
        for (int g = 0; g < 4; ++g) {
            const float4 v0 = *(const float4*)(base + g * 4);
            const float4 v1 = *(const float4*)(base + CH + g * 4);
            const float4 v2 = *(const float4*)(base + HIN * CH + g * 4);
            const float4 v3 = *(const float4*)(base + HIN * CH + CH + g * 4);
            float m0, m1, m2, m3;
            uint32_t k0, k1, k2, k3;
            { float best = v0.x; uint32_t k = 0;
              if (v1.x > best) { best = v1.x; k = 1; }
              if (v2.x > best) { best = v2.x; k = 2; }
              if (v3.x > best) { best = v3.x; k = 3; }
              m0 = best; k0 = k; }
            { float best = v0.y; uint32_t k = 0;
              if (v1.y > best) { best = v1.y; k = 1; }
              if (v2.y > best) { best = v2.y; k = 2; }
              if (v3.y > best) { best = v3.y; k = 3; }
              m1 = best; k1 = k; }
            { float best = v0.z; uint32_t k = 0;
              if (v1.z > best) { best = v1.z; k = 1; }
              if (v2.z > best) { best = v2.z; k = 2; }
              if (v3.z > best) { best = v3.z; k = 3; }
              m2 = best; k2 = k; }
            { float best = v0.w; uint32_t k = 0;
              if (v1.w > best) { best = v1.w; k = 1; }
              if (v2.w > best) { best = v2.w; k = 2; }
              if (v3.w > best) { best = v3.w; k = 3; }
              m3 = best; k3 = k; }
            kqh |= (k0 << (2 * (g * 4 + 0))) | (k1 << (2 * (g * 4 + 1))) |
                   (k2 << (2 * (g * 4 + 2))) | (k3 << (2 * (g * 4 + 3)));
            if (q2 == p) {
                *(float4*)(mu_out + ((size_t)b * NOUT + p) * CH + hf * 16 + g * 4) =
                    make_float4(m0, m1, m2, m3);
            }
        }
        const uint32_t qb = (uint32_t)(q2 * CH) << 16;
        const uint32_t jb = (uint32_t)(2 * qy) * HIN + 2u * qx;
        #pragma unroll
        for (int dj = 0; dj < 4; ++dj) {
            uint32_t mm = 0;
            #pragma unroll
            for (int cl = 0; cl < 16; ++cl)
                mm |= (((kqh >> (2 * cl)) & 3u) == (uint32_t)dj) ? (1u << cl) : 0u;
            const uint32_t j = jb + (uint32_t)(dj >> 1) * HIN + (dj & 1);
            cmq[j * 2 + hf] = qb | mm;
        }
    }
    __syncthreads();

    // ---------------- per-thread constants + row masks ----------------------
    const uint32_t itm  = (uint32_t)tid & 7u;          // 16B chunk in 128B row
    const uint32_t hs   = itm * 4u;                    // word offset in row
    const uint32_t half = itm >> 2;
    const uint32_t shs  = (itm & 3u) * 4u;
    const uint32_t posb = ((uint32_t)tid >> 6) * 56u + (((uint32_t)tid >> 3) & 7u);
    const int py = p / HO, px = p - py * HO;
    const uint32_t ibase = (uint32_t)(2 * py) * HIN + 2u * px;

    unsigned long long rmpack = 0ull;                  // 4 x 16-bit row masks
    #pragma unroll
    for (int r = 0; r < 4; ++r) {
        const uint32_t jp = ibase + (uint32_t)(r >> 1) * HIN + (r & 1);
        rmpack |= (unsigned long long)(cmq[jp * 2 + half] & 0xFFFFu) << (16 * r);
    }

    // ---------------- Phase 1: dense wave-burst stream + LDS scatter --------
    const float* sb = sigma_in + (size_t)b * NIN * NIN * CH;
    const uint32_t trash = TILE_W + ((uint32_t)tid & 63u);

    for (int o = 0; o < OUTER; ++o) {
        f32x4    val[UNROLL];
        uint32_t tab[UNROLL];
        uint32_t rmv[UNROLL];
        #pragma unroll
        for (int u = 0; u < UNROLL; ++u) {
            const uint32_t pos = (uint32_t)o * WPI + (uint32_t)u * 8u + posb;
            const uint32_t r   = pos / NIN;            // magic-mul
            const uint32_t j   = pos - r * NIN;
            const uint32_t i   = ibase + (r >> 1) * HIN + (r & 1u);
            val[u] = *(const f32x4*)(sb + (((size_t)i * NIN + j) << 5) + hs);
            tab[u] = cmq[j * 2 + half];
            rmv[u] = (uint32_t)(rmpack >> (r * 16u)) & 0xFFFFu;
        }
        #pragma unroll
        for (int u = 0; u < UNROLL; ++u) {
            const uint32_t sel16 = rmv[u] & (tab[u] & 0xFFFFu);
            const uint32_t s4    = (sel16 >> shs) & 0xFu;
            const uint32_t qb    = tab[u] >> 16;       // q*CH
            const uint32_t rot   = (qb >> 3) & 31u;    // q*4 mod 32
            const uint32_t base0 = qb + ((hs + rot) & 31u);
            // 4 contiguous words (no mod-32 wrap: hs+3 <= 31 pre-rotation,
            // and rotation keeps them contiguous within the row via &31 below)
            out_tile[(s4 & 1u) ? qb + ((hs + 0u + rot) & 31u) : trash] = val[u][0];
            out_tile[(s4 & 2u) ? qb + ((hs + 1u + rot) & 31u) : trash] = val[u][1];
            out_tile[(s4 & 4u) ? qb + ((hs + 2u + rot) & 31u) : trash] = val[u][2];
            out_tile[(s4 & 8u) ? qb + ((hs + 3u + rot) & 31u) : trash] = val[u][3];
            (void)base0;
        }
    }
    __syncthreads();

    // ---------------- Phase 2: un-rotate + coalesced NT write-out -----------
    {
        f32x4* dstT = (f32x4*)(sigma_out + ((size_t)b * NOUT + p) * TILE_W);
        for (int w = tid; w < TILE_W / 4; w += 256) {  // 1568 f32x4
            const uint32_t q   = (uint32_t)w >> 3;
            const uint32_t v   = ((uint32_t)w & 7u) * 4u;
            const uint32_t rot = (q * 4u) & 31u;
            const f32x4 x = *(const f32x4*)(out_tile + q * 32u + ((v + rot) & 31u));
            __builtin_nontemporal_store(x, &dstT[w]);
        }
    }
}

extern "C" void kernel_launch(void* const* d_in, const int* in_sizes, int n_in,
                              void* d_out, int out_size, void* d_ws, size_t ws_size,
                              hipStream_t stream) {
    const float* mu_in    = (const float*)d_in[0];
    const float* sigma_in = (const float*)d_in[1];

    float* mu_out    = (float*)d_out;                      // 8*14*14*32 floats
    float* sigma_out = (float*)d_out + BATCH * NOUT * CH;  // 8*196*196*32 floats

    vdp_pool_fused_kernel<<<BATCH * NOUT, 256, 0, stream>>>(
        mu_in, sigma_in, mu_out, sigma_out);
}

// Round 9
// 132.107 us; speedup vs baseline: 1.1110x; 1.1110x over previous
//
#include <hip/hip_runtime.h>
#include <stdint.h>

#define BATCH 8
#define HIN   28
#define CH    32
#define HO    14
#define NIN   784                 // 28*28
#define NOUT  196                 // 14*14
#define ROW_W   (NIN * CH)        // 25088 floats per Sigma spatial row (100KB)
#define JH      392               // j-positions per half
#define STAGE_W (JH * CH)         // 12544 floats = 50176 B staged per r
#define NCHUNK  49                // 1KB DMA chunks per half-row
#define TILE_W  (NOUT * CH)       // 6272 output words per (b,p)

typedef float f32x4 __attribute__((ext_vector_type(4)));

#if defined(__has_builtin)
#if __has_builtin(__builtin_amdgcn_global_load_lds)
#define HAS_GLDS 1
#endif
#endif

// Block = (b, p, jhalf). Phase 0: argmax codes for all windows of image b
// (mu is L2/L3-hot) -> colsel[q*32+c] = flat input col selected by (q,c);
// own-p threads write mu_out (both jhalf blocks write identical values).
// Main loop over r=0..3 (the 4 candidate input rows of window p):
//   DMA:    stage the 50KB half-row Sigma[i_r, jlo:jlo+392, :] densely into
//           LDS via global_load_lds (wave-uniform dest, lane*16B, zero
//           address VALU, all chunks async in flight) -> __syncthreads.
//   GATHER: thread owns words (q = tid>>5 + 32k, c = tid&31); value lives at
//           stage[(colsel[q*32+c]-jlo)*32 + c] iff colsel[p*32+c]==i_r and
//           the col falls in this block's half. 7 conflict-free ds_read_b32
//           (bank = c -> 2-way = free) + cndmask into register acc.
// Store: predicated coalesced nontemporal stores; each global word is
// written by exactly one (r, jhalf) -> no init, no atomics, deterministic.
__global__ __launch_bounds__(1024, 8) void vdp_pool_dma_kernel(
        const float* __restrict__ mu_in,
        const float* __restrict__ sigma_in,
        float* __restrict__ mu_out,
        float* __restrict__ sigma_out)
{
    __shared__ __align__(16) float stage[STAGE_W];   // 50176 B
    __shared__ uint16_t colsel[TILE_W];              // 12544 B

    const int bid = blockIdx.x;
    const int jh  = bid & 1;                 // j-half
    const int bp  = bid >> 1;                // b*NOUT + p
    const int b   = bp / NOUT;
    const int p   = bp - b * NOUT;
    const int tid = threadIdx.x;

    // ---------------- Phase 0: window codes -> colsel (+ mu_out) -----------
    if (tid < NOUT * 2) {
        const int q2 = tid >> 1, hf = tid & 1;
        const int qy = q2 / HO, qx = q2 - qy * HO;
        const float* base =
            mu_in + (((size_t)b * HIN + 2 * qy) * HIN + 2 * qx) * CH + hf * 16;
        const int jb = (2 * qy) * HIN + 2 * qx;

        #pragma unroll
        for (int g = 0; g < 4; ++g) {
            const float4 v0 = *(const float4*)(base + g * 4);
            const float4 v1 = *(const float4*)(base + CH + g * 4);
            const float4 v2 = *(const float4*)(base + HIN * CH + g * 4);
            const float4 v3 = *(const float4*)(base + HIN * CH + CH + g * 4);
            float m0, m1, m2, m3;
            uint32_t k0, k1, k2, k3;
            { float best = v0.x; uint32_t k = 0;
              if (v1.x > best) { best = v1.x; k = 1; }      // strict > : TF ties
              if (v2.x > best) { best = v2.x; k = 2; }
              if (v3.x > best) { best = v3.x; k = 3; }
              m0 = best; k0 = k; }
            { float best = v0.y; uint32_t k = 0;
              if (v1.y > best) { best = v1.y; k = 1; }
              if (v2.y > best) { best = v2.y; k = 2; }
              if (v3.y > best) { best = v3.y; k = 3; }
              m1 = best; k1 = k; }
            { float best = v0.z; uint32_t k = 0;
              if (v1.z > best) { best = v1.z; k = 1; }
              if (v2.z > best) { best = v2.z; k = 2; }
              if (v3.z > best) { best = v3.z; k = 3; }
              m2 = best; k2 = k; }
            { float best = v0.w; uint32_t k = 0;
              if (v1.w > best) { best = v1.w; k = 1; }
              if (v2.w > best) { best = v2.w; k = 2; }
              if (v3.w > best) { best = v3.w; k = 3; }
              m3 = best; k3 = k; }
            const int cb = q2 * CH + hf * 16 + g * 4;
            colsel[cb + 0] = (uint16_t)(jb + (int)(k0 >> 1) * HIN + (int)(k0 & 1));
            colsel[cb + 1] = (uint16_t)(jb + (int)(k1 >> 1) * HIN + (int)(k1 & 1));
            colsel[cb + 2] = (uint16_t)(jb + (int)(k2 >> 1) * HIN + (int)(k2 & 1));
            colsel[cb + 3] = (uint16_t)(jb + (int)(k3 >> 1) * HIN + (int)(k3 & 1));
            if (q2 == p) {
                *(float4*)(mu_out + (size_t)bp * CH + hf * 16 + g * 4) =
                    make_float4(m0, m1, m2, m3);
            }
        }
    }
    __syncthreads();

    // ---------------- per-thread constants ----------------------------------
    const int c    = tid & 31;               // channel
    const int qb0  = tid >> 5;               // 0..31
    const int lane = tid & 63;
    const int wave = tid >> 6;               // 0..15
    const int jlo  = jh * JH;

    uint16_t jcol[7];
    #pragma unroll
    for (int k = 0; k < 7; ++k) {
        const int q = qb0 + 32 * k;
        jcol[k] = (q < NOUT) ? colsel[q * CH + c] : (uint16_t)0;
    }
    const int jrow = (int)colsel[p * CH + c];   // selected input row for (p,c)

    const int py = p / HO, px = p - py * HO;
    float acc[7] = {0, 0, 0, 0, 0, 0, 0};

    // ---------------- main loop over the 4 candidate rows -------------------
    for (int r = 0; r < 4; ++r) {
        const int i_r = (2 * py + (r >> 1)) * HIN + 2 * px + (r & 1);
        const float* rowb =
            sigma_in + ((size_t)b * NIN + i_r) * ROW_W + (size_t)jlo * CH;

        // DMA the 50KB half-row into LDS, dense, wave-uniform dest
#ifdef HAS_GLDS
        #pragma unroll
        for (int k = 0; k < 4; ++k) {
            const int ck = wave + 16 * k;
            if (ck < NCHUNK)
                __builtin_amdgcn_global_load_lds(
                    (const __attribute__((address_space(1))) void*)
                        (rowb + ck * 256 + lane * 4),
                    (__attribute__((address_space(3))) void*)
                        (stage + ck * 256 + lane * 4),
                    16, 0, 0);
        }
#else
        f32x4 tmp[4];
        #pragma unroll
        for (int k = 0; k < 4; ++k) {
            const int ck = wave + 16 * k;
            tmp[k] = (ck < NCHUNK)
                ? *(const f32x4*)(rowb + ck * 256 + lane * 4)
                : (f32x4){0, 0, 0, 0};
        }
        #pragma unroll
        for (int k = 0; k < 4; ++k) {
            const int ck = wave + 16 * k;
            if (ck < NCHUNK)
                *(f32x4*)(stage + ck * 256 + lane * 4) = tmp[k];
        }
#endif
        __syncthreads();                     // drains vmcnt -> stage ready

        const bool rhit = (jrow == i_r);
        #pragma unroll
        for (int k = 0; k < 7; ++k) {
            const int jl    = (int)jcol[k] - jlo;
            const bool mine = (jl >= 0) && (jl < JH);
            const int  ja   = mine ? jl : 0;
            const float v   = stage[ja * CH + c];     // bank=c -> 2-way, free
            acc[k] = (rhit && mine) ? v : acc[k];
        }
        __syncthreads();                     // gather done before next DMA
    }

    // ---------------- store: one owner per word, coalesced NT ---------------
    float* ob = sigma_out + (size_t)bp * TILE_W;
    #pragma unroll
    for (int k = 0; k < 7; ++k) {
        const int q  = qb0 + 32 * k;
        const int jl = (int)jcol[k] - jlo;
        if (q < NOUT && jl >= 0 && jl < JH)
            __builtin_nontemporal_store(acc[k], ob + q * CH + c);
    }
}

extern "C" void kernel_launch(void* const* d_in, const int* in_sizes, int n_in,
                              void* d_out, int out_size, void* d_ws, size_t ws_size,
                              hipStream_t stream) {
    const float* mu_in    = (const float*)d_in[0];
    const float* sigma_in = (const float*)d_in[1];

    float* mu_out    = (float*)d_out;                      // 8*14*14*32 floats
    float* sigma_out = (float*)d_out + BATCH * NOUT * CH;  // 8*196*196*32 floats

    vdp_pool_dma_kernel<<<BATCH * NOUT * 2, 1024, 0, stream>>>(
        mu_in, sigma_in, mu_out, sigma_out);
}